// Round 4
// baseline (303.311 us; speedup 1.0000x reference)
//
#include <hip/hip_runtime.h>
#include <stdint.h>
#include <math.h>

#define BB 2
#define TT 2048
#define CC 1024
#define NH 16
#define HD 64
#define N3 (3*CC)
#define NT (TT/64)      // 32 K-tiles / Q-tiles
#define SPAD 74         // LDS row stride (ushorts): odd dword multiple

typedef __attribute__((ext_vector_type(8))) short bf16x8;
typedef __attribute__((ext_vector_type(4))) float f32x4;

__device__ inline ushort f2bf(float f) {
  uint32_t u = __float_as_uint(f);
  u += 0x7fff + ((u >> 16) & 1);          // RNE
  return (ushort)(u >> 16);
}

// ---------------- cast f32 -> bf16, vectorized ----------------
__global__ __launch_bounds__(256) void cast_bf16_k(const float* __restrict__ in,
                                                   ushort* __restrict__ out, int n)
{
  int i = (blockIdx.x * 256 + threadIdx.x) * 4;
  if (i + 3 < n) {
    float4 v = *(const float4*)(in + i);
    ushort4 o;
    o.x = f2bf(v.x); o.y = f2bf(v.y); o.z = f2bf(v.z); o.w = f2bf(v.w);
    *(ushort4*)(out + i) = o;
  }
}

// ---------------- bf16 MFMA GEMM: C[M,N] = A[M,K] @ W[N,K]^T + bias --------
#define GLDK 40   // 32 + 8 pad (bf16 elems)

template<bool OUT_BF16>
__global__ __launch_bounds__(256) void gemm_mfma(
    const ushort* __restrict__ A, const ushort* __restrict__ W,
    const float* __restrict__ bias, void* __restrict__ Cout,
    int M, int N, int K)
{
  __shared__ ushort As[128 * GLDK];
  __shared__ ushort Ws[128 * GLDK];
  const int tid = threadIdx.x;
  const int lane = tid & 63, wave = tid >> 6;
  const int wr = (wave >> 1) * 64, wc = (wave & 1) * 64;
  const int bm = blockIdx.y * 128, bn = blockIdx.x * 128;
  const int fr = lane & 15, kg = (lane >> 4) * 8, rg = (lane >> 4) * 4;
  const int srow = tid >> 1, skb = (tid & 1) * 16;
  f32x4 acc[4][4];
  #pragma unroll
  for (int m = 0; m < 4; ++m)
    #pragma unroll
    for (int n = 0; n < 4; ++n) acc[m][n] = (f32x4){0.f, 0.f, 0.f, 0.f};

  const ushort* ag = A + (size_t)(bm + srow) * K + skb;
  const ushort* wg = W + (size_t)(bn + srow) * K + skb;
  for (int k0 = 0; k0 < K; k0 += 32) {
    bf16x8 a0 = *(const bf16x8*)(ag + k0);
    bf16x8 a1 = *(const bf16x8*)(ag + k0 + 8);
    bf16x8 w0 = *(const bf16x8*)(wg + k0);
    bf16x8 w1 = *(const bf16x8*)(wg + k0 + 8);
    __syncthreads();
    *(bf16x8*)&As[srow * GLDK + skb]     = a0;
    *(bf16x8*)&As[srow * GLDK + skb + 8] = a1;
    *(bf16x8*)&Ws[srow * GLDK + skb]     = w0;
    *(bf16x8*)&Ws[srow * GLDK + skb + 8] = w1;
    __syncthreads();
    bf16x8 af[4], wf[4];
    #pragma unroll
    for (int m = 0; m < 4; ++m) af[m] = *(const bf16x8*)&As[(wr + m*16 + fr) * GLDK + kg];
    #pragma unroll
    for (int n = 0; n < 4; ++n) wf[n] = *(const bf16x8*)&Ws[(wc + n*16 + fr) * GLDK + kg];
    #pragma unroll
    for (int m = 0; m < 4; ++m)
      #pragma unroll
      for (int n = 0; n < 4; ++n)
        acc[m][n] = __builtin_amdgcn_mfma_f32_16x16x32_bf16(af[m], wf[n], acc[m][n], 0, 0, 0);
  }
  #pragma unroll
  for (int n = 0; n < 4; ++n) {
    const int col = bn + wc + n*16 + fr;
    const float bv = bias[col];
    #pragma unroll
    for (int m = 0; m < 4; ++m)
      #pragma unroll
      for (int r = 0; r < 4; ++r) {
        const int row = bm + wr + m*16 + rg + r;
        const float v = acc[m][n][r] + bv;
        if (OUT_BF16) ((ushort*)Cout)[(size_t)row * N + col] = f2bf(v);
        else          ((float*)Cout)[(size_t)row * N + col]  = v;
      }
  }
}

// ---------------- head-0 scores via MFMA: S = mask(relu(q0 k0^T /8)) -------
__global__ __launch_bounds__(256) void s_scores_mfma(
    const ushort* __restrict__ qkvb, float* __restrict__ SF)
{
  const int jc = blockIdx.x, it = blockIdx.y, b = blockIdx.z;
  if (jc * 8 > it) return;
  __shared__ ushort Qs[64 * SPAD], Ks[64 * SPAD];
  const int tid = threadIdx.x, lane = tid & 63, wave = tid >> 6;
  const int i0 = it * 64;
  const int fr = lane & 15, kg = (lane >> 4) * 8, rg = (lane >> 4) * 4;
  const int srow = tid >> 2, sd = (tid & 3) * 16;
  {
    const ushort* g = qkvb + (size_t)(b*TT + i0 + srow) * N3 + sd;   // head0 q
    bf16x8 v0 = *(const bf16x8*)g, v1 = *(const bf16x8*)(g + 8);
    *(bf16x8*)&Qs[srow*SPAD + sd]     = v0;
    *(bf16x8*)&Qs[srow*SPAD + sd + 8] = v1;
  }
  const int jt1 = min(jc*8 + 7, it);
  for (int jt = jc*8; jt <= jt1; ++jt) {
    const int j0 = jt * 64;
    __syncthreads();
    {
      const ushort* g = qkvb + (size_t)(b*TT + j0 + srow) * N3 + CC + sd;  // head0 k
      bf16x8 v0 = *(const bf16x8*)g, v1 = *(const bf16x8*)(g + 8);
      *(bf16x8*)&Ks[srow*SPAD + sd]     = v0;
      *(bf16x8*)&Ks[srow*SPAD + sd + 8] = v1;
    }
    __syncthreads();
    bf16x8 qf[2];
    #pragma unroll
    for (int kc = 0; kc < 2; ++kc) qf[kc] = *(const bf16x8*)&Qs[(wave*16 + fr)*SPAD + kc*32 + kg];
    #pragma unroll
    for (int n = 0; n < 4; ++n) {
      f32x4 s = (f32x4){0.f, 0.f, 0.f, 0.f};
      #pragma unroll
      for (int kc = 0; kc < 2; ++kc) {
        bf16x8 kf = *(const bf16x8*)&Ks[(n*16 + fr)*SPAD + kc*32 + kg];
        s = __builtin_amdgcn_mfma_f32_16x16x32_bf16(qf[kc], kf, s, 0, 0, 0);
      }
      const int cg = j0 + n*16 + fr;
      #pragma unroll
      for (int r = 0; r < 4; ++r) {
        const int rgg = i0 + wave*16 + rg + r;
        float v = s[r] * 0.125f;
        v = (cg < rgg && cg != 0) ? fmaxf(v, 0.f) : 0.f;   // causal<, col0, diag -> 0
        SF[((size_t)b*TT + rgg)*TT + cg] = v;
      }
    }
  }
}

// ---------------- FF = exclusive column-prefix of S (3-phase scan) ---------
__global__ __launch_bounds__(256) void ff_pass1(const float* __restrict__ SF,
                                                float* __restrict__ part)
{
  const int jg = blockIdx.x & 7, ch = (blockIdx.x >> 3) & 15, b = blockIdx.x >> 7;
  const int j = jg*256 + threadIdx.x;
  const float* p = SF + ((size_t)b*TT + ch*128)*TT + j;
  float s = 0.f;
  for (int i = 0; i < 128; ++i) s += p[(size_t)i*TT];
  part[(b*16 + ch)*TT + j] = s;
}

__global__ __launch_bounds__(256) void ff_pass2(float* __restrict__ SF,
                                                const float* __restrict__ part)
{
  const int jg = blockIdx.x & 7, ch = (blockIdx.x >> 3) & 15, b = blockIdx.x >> 7;
  const int j = jg*256 + threadIdx.x;
  float acc = 0.f;
  for (int c = 0; c < ch; ++c) acc += part[(b*16 + c)*TT + j];
  float* p = SF + ((size_t)b*TT + ch*128)*TT + j;
  for (int i = 0; i < 128; ++i) {
    const float v = p[(size_t)i*TT];
    p[(size_t)i*TT] = acc;
    acc += v;
  }
}

// ---------------- dense flash attention, paired Q-tiles ---------------------
// grid (pair=16, b*NH=32); block 256 = 4 waves; pair (a, 31-a) shares K/V.
__device__ __forceinline__ void attn_tile_step(
    const bf16x8 qf[2], const ushort* Ks, const ushort* Vt, ushort* Ps,
    const float* __restrict__ FFb, int i0ws, int j0, bool diag,
    int fr, int kg, int rg,
    f32x4 o[4], float m_run[4], float l_run[4])
{
  float p[4][4];
  float mx[4] = {-INFINITY, -INFINITY, -INFINITY, -INFINITY};
  #pragma unroll
  for (int n = 0; n < 4; ++n) {
    f32x4 s = (f32x4){0.f, 0.f, 0.f, 0.f};
    #pragma unroll
    for (int kc = 0; kc < 2; ++kc) {
      bf16x8 kf = *(const bf16x8*)&Ks[(n*16 + fr)*SPAD + kc*32 + kg];
      s = __builtin_amdgcn_mfma_f32_16x16x32_bf16(qf[kc], kf, s, 0, 0, 0);
    }
    const int cg = j0 + n*16 + fr;
    #pragma unroll
    for (int r = 0; r < 4; ++r) {
      const int rgg = i0ws + rg + r;
      float lg = s[r] * 0.125f - FFb[(size_t)rgg*TT + cg];
      if (diag) lg = (cg <= rgg) ? lg : -INFINITY;
      p[n][r] = lg;
      mx[r] = fmaxf(mx[r], lg);
    }
  }
  #pragma unroll
  for (int r = 0; r < 4; ++r)
    #pragma unroll
    for (int d = 1; d < 16; d <<= 1) mx[r] = fmaxf(mx[r], __shfl_xor(mx[r], d));
  float scale[4], rs[4];
  #pragma unroll
  for (int r = 0; r < 4; ++r) {
    const float mn = fmaxf(m_run[r], mx[r]);
    scale[r] = __expf(m_run[r] - mn);
    m_run[r] = mn;
    rs[r] = 0.f;
  }
  #pragma unroll
  for (int n = 0; n < 4; ++n)
    #pragma unroll
    for (int r = 0; r < 4; ++r) {
      const float pe = __expf(p[n][r] - m_run[r]);
      p[n][r] = pe;
      rs[r] += pe;
    }
  #pragma unroll
  for (int r = 0; r < 4; ++r) {
    #pragma unroll
    for (int d = 1; d < 16; d <<= 1) rs[r] += __shfl_xor(rs[r], d);
    l_run[r] = l_run[r] * scale[r] + rs[r];
  }
  #pragma unroll
  for (int ds = 0; ds < 4; ++ds)
    #pragma unroll
    for (int r = 0; r < 4; ++r) o[ds][r] *= scale[r];
  const int ws16 = i0ws;  (void)ws16;
  #pragma unroll
  for (int n = 0; n < 4; ++n)
    #pragma unroll
    for (int r = 0; r < 4; ++r)
      Ps[(rg + r)*SPAD + n*16 + fr] = f2bf(p[n][r]);   // wave-local rows 0..15
  #pragma unroll
  for (int ds = 0; ds < 4; ++ds)
    #pragma unroll
    for (int kc = 0; kc < 2; ++kc) {
      bf16x8 pf = *(const bf16x8*)&Ps[fr*SPAD + kc*32 + kg];
      bf16x8 vf = *(const bf16x8*)&Vt[(ds*16 + fr)*SPAD + kc*32 + kg];
      o[ds] = __builtin_amdgcn_mfma_f32_16x16x32_bf16(pf, vf, o[ds], 0, 0, 0);
    }
}

__global__ __launch_bounds__(256) void flash_attn2(
    const ushort* __restrict__ qkvb, const float* __restrict__ FF,
    ushort* __restrict__ Yb)
{
  const int pa = blockIdx.x;                  // 0..15
  const int b = blockIdx.y >> 4, h = blockIdx.y & 15;
  const int itA = pa, itB = NT - 1 - pa;
  __shared__ ushort Ks[64*SPAD], Vt[64*SPAD], PsA[4][16*SPAD], PsB[4][16*SPAD];
  const int tid = threadIdx.x, lane = tid & 63, wave = tid >> 6;
  const int ws = wave * 16;
  const int fr = lane & 15, kg = (lane >> 4) * 8, rg = (lane >> 4) * 4;
  const float* FFb = FF + (size_t)b*TT*TT;

  // Q fragments in registers (A-frag: row = ws+fr, cols kc*32+kg..+7)
  bf16x8 qA[2], qB[2];
  #pragma unroll
  for (int kc = 0; kc < 2; ++kc) {
    qA[kc] = *(const bf16x8*)(qkvb + (size_t)(b*TT + itA*64 + ws + fr)*N3 + h*HD + kc*32 + kg);
    qB[kc] = *(const bf16x8*)(qkvb + (size_t)(b*TT + itB*64 + ws + fr)*N3 + h*HD + kc*32 + kg);
  }
  f32x4 oA[4], oB[4];
  float mA[4], lA[4], mB[4], lB[4];
  #pragma unroll
  for (int r = 0; r < 4; ++r) {
    mA[r] = -INFINITY; lA[r] = 0.f; mB[r] = -INFINITY; lB[r] = 0.f;
    oA[r] = (f32x4){0.f,0.f,0.f,0.f}; oB[r] = (f32x4){0.f,0.f,0.f,0.f};
  }
  const int srow = tid >> 2, sd = (tid & 3) * 16;   // K staging
  const int vrow = tid & 63, vd = (tid >> 6) * 16;  // V staging (transpose)

  for (int jt = 0; jt <= itB; ++jt) {
    const int j0 = jt * 64;
    const ushort* gk = qkvb + (size_t)(b*TT + j0 + srow)*N3 + CC + h*HD + sd;
    bf16x8 k0 = *(const bf16x8*)gk, k1 = *(const bf16x8*)(gk + 8);
    const ushort* gv = qkvb + (size_t)(b*TT + j0 + vrow)*N3 + 2*CC + h*HD + vd;
    bf16x8 u0 = *(const bf16x8*)gv, u1 = *(const bf16x8*)(gv + 8);
    __syncthreads();
    *(bf16x8*)&Ks[srow*SPAD + sd]     = k0;
    *(bf16x8*)&Ks[srow*SPAD + sd + 8] = k1;
    #pragma unroll
    for (int e = 0; e < 8; ++e) {                   // conflict-free: row uniform/wave
      Vt[(vd + e)*SPAD + vrow]     = (ushort)u0[e];
      Vt[(vd + 8 + e)*SPAD + vrow] = (ushort)u1[e];
    }
    __syncthreads();
    attn_tile_step(qB, Ks, Vt, PsB[wave], FFb, itB*64 + ws, j0, jt == itB,
                   fr, kg, rg, oB, mB, lB);
    if (jt <= itA)
      attn_tile_step(qA, Ks, Vt, PsA[wave], FFb, itA*64 + ws, j0, jt == itA,
                     fr, kg, rg, oA, mA, lA);
  }
  #pragma unroll
  for (int ds = 0; ds < 4; ++ds)
    #pragma unroll
    for (int r = 0; r < 4; ++r) {
      const int dg = h*HD + ds*16 + fr;
      Yb[(size_t)(b*TT + itA*64 + ws + rg + r)*CC + dg] = f2bf(oA[ds][r] / lA[r]);
      Yb[(size_t)(b*TT + itB*64 + ws + rg + r)*CC + dg] = f2bf(oB[ds][r] / lB[r]);
    }
}

// ---------------------------------------------------------------------------
extern "C" void kernel_launch(void* const* d_in, const int* in_sizes, int n_in,
                              void* d_out, int out_size, void* d_ws, size_t ws_size,
                              hipStream_t stream) {
  const float* x      = (const float*)d_in[0];
  const float* w_attn = (const float*)d_in[1];
  const float* b_attn = (const float*)d_in[2];
  const float* w_proj = (const float*)d_in[3];
  const float* b_proj = (const float*)d_in[4];
  float* out = (float*)d_out;

  // workspace layout (~92.5 MB)
  ushort* xb   = (ushort*)d_ws;                         // B*T*C bf16
  ushort* wab  = xb   + (size_t)BB*TT*CC;               // 3C*C bf16
  ushort* wpb  = wab  + (size_t)N3*CC;                  // C*C bf16
  ushort* qkvb = wpb  + (size_t)CC*CC;                  // B*T*3C bf16
  ushort* Yb   = qkvb + (size_t)BB*TT*N3;               // B*T*C bf16
  float*  SF   = (float*)(Yb + (size_t)BB*TT*CC);       // B*T*T f32 (S then FF)
  float*  part = SF + (size_t)BB*TT*TT;                 // B*16*T f32

  cast_bf16_k<<<(BB*TT*CC/4 + 255)/256, 256, 0, stream>>>(x, xb, BB*TT*CC);
  cast_bf16_k<<<(N3*CC/4 + 255)/256, 256, 0, stream>>>(w_attn, wab, N3*CC);
  cast_bf16_k<<<(CC*CC/4 + 255)/256, 256, 0, stream>>>(w_proj, wpb, CC*CC);

  gemm_mfma<true><<<dim3(N3/128, (BB*TT)/128), 256, 0, stream>>>(
      xb, wab, b_attn, (void*)qkvb, BB*TT, N3, CC);

  hipMemsetAsync(SF, 0, (size_t)BB*TT*TT*sizeof(float), stream);
  s_scores_mfma<<<dim3(4, TT/64, BB), 256, 0, stream>>>(qkvb, SF);

  ff_pass1<<<256, 256, 0, stream>>>(SF, part);
  ff_pass2<<<256, 256, 0, stream>>>(SF, part);

  flash_attn2<<<dim3(NT/2, BB*NH), 256, 0, stream>>>(qkvb, SF, Yb);

  gemm_mfma<false><<<dim3(CC/128, (BB*TT)/128), 256, 0, stream>>>(
      Yb, wpb, b_proj, (void*)out, BB*TT, CC, CC);
}